// Round 1
// baseline (474.805 us; speedup 1.0000x reference)
//
#include <hip/hip_runtime.h>
#include <hip/hip_bf16.h>
#include <stdint.h>

#define D_MODEL 1024
#define HEADS   16
#define DK      64
#define BATCH   4
#define SEQ     2048
#define MROWS   (BATCH * SEQ)  // 8192

typedef __attribute__((ext_vector_type(8))) short bf16x8;
typedef __attribute__((ext_vector_type(4))) float f32x4;
typedef __attribute__((ext_vector_type(4))) unsigned int u32x4;
typedef __attribute__((ext_vector_type(2))) unsigned int u32x2;

__device__ __forceinline__ unsigned short f2bf(float f) {
  union { float f; unsigned int u; } c; c.f = f;
  return (unsigned short)((c.u + 0x7fffu + ((c.u >> 16) & 1u)) >> 16);  // RNE
}

__device__ __forceinline__ void gl_lds16(const void* g, void* l) {
  __builtin_amdgcn_global_load_lds(
      (const __attribute__((address_space(1))) unsigned int*)g,
      (__attribute__((address_space(3))) unsigned int*)l, 16, 0, 0);
}

// ---------------- weight fp32 -> bf16 convert (1M elements) ----------------
__global__ __launch_bounds__(256) void cvt_f32_bf16(const float* __restrict__ in,
                                                    unsigned short* __restrict__ out) {
  const int i = (blockIdx.x * 256 + threadIdx.x) * 4;  // grid covers exactly 1<<20
  f32x4 v = *(const f32x4*)(in + i);
  u32x2 w;
  w[0] = f2bf(v[0]) | ((unsigned)f2bf(v[1]) << 16);
  w[1] = f2bf(v[2]) | ((unsigned)f2bf(v[3]) << 16);
  *(u32x2*)(out + i) = w;
}

// ---------------- GEMM: Y[M,N] = X[M,K] @ W[N,K]^T + b ----------------
// A_FP32: A operand is fp32 (reg-staged + cvt into padded LDS); else bf16 via global_load_lds.
// OUT_FP32: write fp32 (else bf16).
template <int A_FP32, int OUT_FP32>
__global__ __launch_bounds__(256) void gemm128(const void* __restrict__ Ap,
                                               const unsigned short* __restrict__ Bw,
                                               const float* __restrict__ bias,
                                               void* __restrict__ Outp) {
  constexpr int ASTR = A_FP32 ? 40 : 32;  // pad fp32-staged A rows: stride 40 elems -> 2-way banks (free)
  __shared__ unsigned short As[128 * ASTR];
  __shared__ unsigned short Bs[128 * 32];

  const int tid = threadIdx.x;
  const int lane = tid & 63, wid = tid >> 6;
  const int l16 = lane & 15, lg = lane >> 4;
  const int wrow = (wid >> 1) * 64, wcol = (wid & 1) * 64;

  // XCD-aware bijective swizzle (512 blocks % 8 == 0)
  const int bx = blockIdx.x;
  const int swz = (bx & 7) * 64 + (bx >> 3);
  const int m0 = (swz >> 3) * 128, n0 = (swz & 7) * 128;

  f32x4 acc[4][4];
  const f32x4 zero = {0.f, 0.f, 0.f, 0.f};
#pragma unroll
  for (int i = 0; i < 4; ++i)
#pragma unroll
    for (int j = 0; j < 4; ++j) acc[i][j] = zero;

#pragma unroll 1
  for (int kt = 0; kt < D_MODEL / 32; ++kt) {
    const int k0 = kt * 32;
    __syncthreads();
    if constexpr (A_FP32) {
      const float* Af = (const float*)Ap;
      const int ar = tid >> 1, ah = (tid & 1) * 16;
      const float* src = Af + (size_t)(m0 + ar) * D_MODEL + k0 + ah;
      f32x4 v0 = *(const f32x4*)src;
      f32x4 v1 = *(const f32x4*)(src + 4);
      f32x4 v2 = *(const f32x4*)(src + 8);
      f32x4 v3 = *(const f32x4*)(src + 12);
      u32x4 pa, pb;
      pa[0] = f2bf(v0[0]) | ((unsigned)f2bf(v0[1]) << 16);
      pa[1] = f2bf(v0[2]) | ((unsigned)f2bf(v0[3]) << 16);
      pa[2] = f2bf(v1[0]) | ((unsigned)f2bf(v1[1]) << 16);
      pa[3] = f2bf(v1[2]) | ((unsigned)f2bf(v1[3]) << 16);
      pb[0] = f2bf(v2[0]) | ((unsigned)f2bf(v2[1]) << 16);
      pb[1] = f2bf(v2[2]) | ((unsigned)f2bf(v2[3]) << 16);
      pb[2] = f2bf(v3[0]) | ((unsigned)f2bf(v3[1]) << 16);
      pb[3] = f2bf(v3[2]) | ((unsigned)f2bf(v3[3]) << 16);
      *(u32x4*)&As[ar * ASTR + ah] = pa;
      *(u32x4*)&As[ar * ASTR + ah + 8] = pb;
    } else {
      const unsigned short* Ab = (const unsigned short*)Ap;
      const unsigned short* srcb = Ab + (size_t)m0 * D_MODEL + k0;
#pragma unroll
      for (int p = 0; p < 2; ++p) {
        const int e = wid * 512 + p * 2048 + lane * 8;  // element idx in 128x32 tile
        gl_lds16(srcb + (size_t)(e >> 5) * D_MODEL + (e & 31),
                 (char*)As + wid * 1024 + p * 4096);
      }
    }
    {
      const unsigned short* srcb = Bw + (size_t)n0 * D_MODEL + k0;
#pragma unroll
      for (int p = 0; p < 2; ++p) {
        const int e = wid * 512 + p * 2048 + lane * 8;
        gl_lds16(srcb + (size_t)(e >> 5) * D_MODEL + (e & 31),
                 (char*)Bs + wid * 1024 + p * 4096);
      }
    }
    __syncthreads();

    bf16x8 af[4], bfr[4];
#pragma unroll
    for (int i = 0; i < 4; ++i) {
      af[i]  = *(const bf16x8*)&As[(wrow + i * 16 + l16) * ASTR + lg * 8];
      bfr[i] = *(const bf16x8*)&Bs[(wcol + i * 16 + l16) * 32 + lg * 8];
    }
#pragma unroll
    for (int i = 0; i < 4; ++i)
#pragma unroll
      for (int j = 0; j < 4; ++j)
        acc[i][j] = __builtin_amdgcn_mfma_f32_16x16x32_bf16(af[i], bfr[j], acc[i][j], 0, 0, 0);
  }

  // epilogue: + bias, store
#pragma unroll
  for (int j = 0; j < 4; ++j) {
    const int col = n0 + wcol + j * 16 + l16;
    const float bv = bias[col];
#pragma unroll
    for (int i = 0; i < 4; ++i) {
      const int row0 = m0 + wrow + i * 16 + lg * 4;
#pragma unroll
      for (int r = 0; r < 4; ++r) {
        const float y = acc[i][j][r] + bv;
        if constexpr (OUT_FP32)
          ((float*)Outp)[(size_t)(row0 + r) * D_MODEL + col] = y;
        else
          ((unsigned short*)Outp)[(size_t)(row0 + r) * D_MODEL + col] = f2bf(y);
      }
    }
  }
}

// ---------------- flash attention: per (b,h,128-q-block) ----------------
__global__ __launch_bounds__(256) void attn128(const unsigned short* __restrict__ Qb,
                                               const unsigned short* __restrict__ Kb,
                                               const unsigned short* __restrict__ Vb,
                                               unsigned short* __restrict__ Xo) {
  __shared__ unsigned short Qs[128 * 72];
  __shared__ unsigned short Ks[64 * 72];
  __shared__ unsigned short Vt[64 * 72];   // V transposed: [d][t]
  __shared__ unsigned short Ps[4][32 * 72];

  const int tid = threadIdx.x;
  const int lane = tid & 63, w = tid >> 6;
  const int l16 = lane & 15, lg = lane >> 4;
  const int qb = blockIdx.x & 15, bh = blockIdx.x >> 4;
  const int b = bh >> 4, h = bh & 15;

  const size_t srow0 = (size_t)b * SEQ + qb * 128;
  const unsigned short* Qp = Qb + srow0 * D_MODEL + h * DK;
  const unsigned short* Kp = Kb + ((size_t)b * SEQ) * D_MODEL + h * DK;
  const unsigned short* Vp = Vb + ((size_t)b * SEQ) * D_MODEL + h * DK;

  {  // stage Q tile 128x64 (padded stride 72)
    const int r = tid >> 1, hf = (tid & 1) * 32;
    const unsigned short* src = Qp + (size_t)r * D_MODEL + hf;
    u32x4 v0 = *(const u32x4*)src;
    u32x4 v1 = *(const u32x4*)(src + 8);
    u32x4 v2 = *(const u32x4*)(src + 16);
    u32x4 v3 = *(const u32x4*)(src + 24);
    *(u32x4*)&Qs[r * 72 + hf] = v0;
    *(u32x4*)&Qs[r * 72 + hf + 8] = v1;
    *(u32x4*)&Qs[r * 72 + hf + 16] = v2;
    *(u32x4*)&Qs[r * 72 + hf + 24] = v3;
  }
  __syncthreads();

  bf16x8 qfrag[2][2];  // Q-hoist: wave's 32 q-rows x 64 d in registers
#pragma unroll
  for (int qf = 0; qf < 2; ++qf)
#pragma unroll
    for (int kh = 0; kh < 2; ++kh)
      qfrag[qf][kh] = *(const bf16x8*)&Qs[(w * 32 + qf * 16 + l16) * 72 + kh * 32 + lg * 8];

  float mrun[2][4], lrun[2][4];
  f32x4 acco[2][4];
  const f32x4 zero = {0.f, 0.f, 0.f, 0.f};
#pragma unroll
  for (int qf = 0; qf < 2; ++qf) {
#pragma unroll
    for (int r = 0; r < 4; ++r) { mrun[qf][r] = -1e30f; lrun[qf][r] = 0.f; }
#pragma unroll
    for (int df = 0; df < 4; ++df) acco[qf][df] = zero;
  }

  const float SC = 0.125f * 1.4426950408889634f;  // 1/sqrt(dk) * log2(e)

#pragma unroll 1
  for (int kb = 0; kb < SEQ / 64; ++kb) {
    __syncthreads();
    {  // stage K (padded) and V^T
      const int r = tid >> 2, c = (tid & 3) * 16;
      const unsigned short* ks = Kp + (size_t)(kb * 64 + r) * D_MODEL + c;
      u32x4 a0 = *(const u32x4*)ks;
      u32x4 a1 = *(const u32x4*)(ks + 8);
      *(u32x4*)&Ks[r * 72 + c] = a0;
      *(u32x4*)&Ks[r * 72 + c + 8] = a1;
      const unsigned short* vs = Vp + (size_t)(kb * 64 + r) * D_MODEL + c;
      u32x4 b0 = *(const u32x4*)vs;
      u32x4 b1 = *(const u32x4*)(vs + 8);
#pragma unroll
      for (int j = 0; j < 4; ++j) {
        Vt[(c + 2 * j) * 72 + r]     = (unsigned short)(b0[j] & 0xffffu);
        Vt[(c + 2 * j + 1) * 72 + r] = (unsigned short)(b0[j] >> 16);
        Vt[(c + 8 + 2 * j) * 72 + r]     = (unsigned short)(b1[j] & 0xffffu);
        Vt[(c + 8 + 2 * j + 1) * 72 + r] = (unsigned short)(b1[j] >> 16);
      }
    }
    __syncthreads();

    // QK^T: S[32q x 64t] per wave
    f32x4 sc[2][4];
#pragma unroll
    for (int qf = 0; qf < 2; ++qf)
#pragma unroll
      for (int tf = 0; tf < 4; ++tf) sc[qf][tf] = zero;
#pragma unroll
    for (int tf = 0; tf < 4; ++tf) {
      bf16x8 k0 = *(const bf16x8*)&Ks[(tf * 16 + l16) * 72 + lg * 8];
      bf16x8 k1 = *(const bf16x8*)&Ks[(tf * 16 + l16) * 72 + 32 + lg * 8];
#pragma unroll
      for (int qf = 0; qf < 2; ++qf) {
        sc[qf][tf] = __builtin_amdgcn_mfma_f32_16x16x32_bf16(qfrag[qf][0], k0, sc[qf][tf], 0, 0, 0);
        sc[qf][tf] = __builtin_amdgcn_mfma_f32_16x16x32_bf16(qfrag[qf][1], k1, sc[qf][tf], 0, 0, 0);
      }
    }

    // online softmax (wave-parallel: 16-lane shfl reduce per q-row)
#pragma unroll
    for (int qf = 0; qf < 2; ++qf)
#pragma unroll
      for (int r = 0; r < 4; ++r) {
        float v = fmaxf(fmaxf(sc[qf][0][r], sc[qf][1][r]), fmaxf(sc[qf][2][r], sc[qf][3][r]));
        v = fmaxf(v, __shfl_xor(v, 1));
        v = fmaxf(v, __shfl_xor(v, 2));
        v = fmaxf(v, __shfl_xor(v, 4));
        v = fmaxf(v, __shfl_xor(v, 8));
        const float mnew = fmaxf(mrun[qf][r], v * SC);
        const float resc = __builtin_amdgcn_exp2f(mrun[qf][r] - mnew);
        mrun[qf][r] = mnew;
#pragma unroll
        for (int df = 0; df < 4; ++df) acco[qf][df][r] *= resc;
        float sum = 0.f;
#pragma unroll
        for (int tf = 0; tf < 4; ++tf) {
          const float p = __builtin_amdgcn_exp2f(sc[qf][tf][r] * SC - mnew);
          sc[qf][tf][r] = p;
          sum += p;
        }
        sum += __shfl_xor(sum, 1);
        sum += __shfl_xor(sum, 2);
        sum += __shfl_xor(sum, 4);
        sum += __shfl_xor(sum, 8);
        lrun[qf][r] = lrun[qf][r] * resc + sum;
      }

    // P -> LDS (C-layout scatter), reload as A-frags
    unsigned short* pw = Ps[w];
#pragma unroll
    for (int qf = 0; qf < 2; ++qf)
#pragma unroll
      for (int tf = 0; tf < 4; ++tf)
#pragma unroll
        for (int r = 0; r < 4; ++r)
          pw[(qf * 16 + lg * 4 + r) * 72 + tf * 16 + l16] = f2bf(sc[qf][tf][r]);

    bf16x8 pf[2][2];
#pragma unroll
    for (int qf = 0; qf < 2; ++qf)
#pragma unroll
      for (int k2 = 0; k2 < 2; ++k2)
        pf[qf][k2] = *(const bf16x8*)&pw[(qf * 16 + l16) * 72 + k2 * 32 + lg * 8];

    // PV: O += P @ V
#pragma unroll
    for (int df = 0; df < 4; ++df) {
      bf16x8 v0 = *(const bf16x8*)&Vt[(df * 16 + l16) * 72 + lg * 8];
      bf16x8 v1 = *(const bf16x8*)&Vt[(df * 16 + l16) * 72 + 32 + lg * 8];
#pragma unroll
      for (int qf = 0; qf < 2; ++qf) {
        acco[qf][df] = __builtin_amdgcn_mfma_f32_16x16x32_bf16(pf[qf][0], v0, acco[qf][df], 0, 0, 0);
        acco[qf][df] = __builtin_amdgcn_mfma_f32_16x16x32_bf16(pf[qf][1], v1, acco[qf][df], 0, 0, 0);
      }
    }
  }

  // finalize: /= l, store bf16 to X (layout [B*S, H*DK])
  unsigned short* dst = Xo + srow0 * D_MODEL + h * DK;
#pragma unroll
  for (int qf = 0; qf < 2; ++qf)
#pragma unroll
    for (int r = 0; r < 4; ++r) {
      const float inv = 1.f / lrun[qf][r];
      const int row = w * 32 + qf * 16 + lg * 4 + r;
#pragma unroll
      for (int df = 0; df < 4; ++df)
        dst[(size_t)row * D_MODEL + df * 16 + l16] = f2bf(acco[qf][df][r] * inv);
    }
}

extern "C" void kernel_launch(void* const* d_in, const int* in_sizes, int n_in,
                              void* d_out, int out_size, void* d_ws, size_t ws_size,
                              hipStream_t stream) {
  const float* query = (const float*)d_in[0];
  const float* key_  = (const float*)d_in[1];
  const float* value = (const float*)d_in[2];
  const float* Wq = (const float*)d_in[3];
  const float* bq = (const float*)d_in[4];
  const float* Wk = (const float*)d_in[5];
  const float* bk = (const float*)d_in[6];
  const float* Wv = (const float*)d_in[7];
  const float* bv = (const float*)d_in[8];
  const float* Wo = (const float*)d_in[9];
  const float* bo = (const float*)d_in[10];

  // workspace layout (bf16 elements): 4x 1M weights, 4x 8M activations = 72 MB
  unsigned short* ws  = (unsigned short*)d_ws;
  unsigned short* WqB = ws;
  unsigned short* WkB = WqB + (1u << 20);
  unsigned short* WvB = WkB + (1u << 20);
  unsigned short* WoB = WvB + (1u << 20);
  unsigned short* Qb  = WoB + (1u << 20);
  unsigned short* Kb  = Qb + (size_t)MROWS * D_MODEL;
  unsigned short* Vb  = Kb + (size_t)MROWS * D_MODEL;
  unsigned short* Xb  = Vb + (size_t)MROWS * D_MODEL;
  if (ws_size < (size_t)(4u * (1u << 20) + 4u * (size_t)MROWS * D_MODEL) * 2u) return;

  cvt_f32_bf16<<<1024, 256, 0, stream>>>(Wq, WqB);
  cvt_f32_bf16<<<1024, 256, 0, stream>>>(Wk, WkB);
  cvt_f32_bf16<<<1024, 256, 0, stream>>>(Wv, WvB);
  cvt_f32_bf16<<<1024, 256, 0, stream>>>(Wo, WoB);

  gemm128<1, 0><<<512, 256, 0, stream>>>(query, WqB, bq, Qb);
  gemm128<1, 0><<<512, 256, 0, stream>>>(key_,  WkB, bk, Kb);
  gemm128<1, 0><<<512, 256, 0, stream>>>(value, WvB, bv, Vb);

  attn128<<<1024, 256, 0, stream>>>(Qb, Kb, Vb, Xb);

  gemm128<0, 1><<<512, 256, 0, stream>>>(Xb, WoB, bo, (float*)d_out);
}

// Round 2
// 304.532 us; speedup vs baseline: 1.5591x; 1.5591x over previous
//
#include <hip/hip_runtime.h>
#include <hip/hip_bf16.h>
#include <stdint.h>

#define D_MODEL 1024
#define HEADS   16
#define DK      64
#define BATCH   4
#define SEQ     2048
#define MROWS   (BATCH * SEQ)  // 8192

typedef __attribute__((ext_vector_type(8))) short bf16x8;
typedef __attribute__((ext_vector_type(4))) float f32x4;
typedef __attribute__((ext_vector_type(4))) unsigned int u32x4;
typedef __attribute__((ext_vector_type(2))) unsigned int u32x2;

__device__ __forceinline__ unsigned short f2bf(float f) {
  union { float f; unsigned int u; } c; c.f = f;
  return (unsigned short)((c.u + 0x7fffu + ((c.u >> 16) & 1u)) >> 16);  // RNE
}

__device__ __forceinline__ void gl_lds16(const void* g, void* l) {
  __builtin_amdgcn_global_load_lds(
      (const __attribute__((address_space(1))) unsigned int*)g,
      (__attribute__((address_space(3))) unsigned int*)l, 16, 0, 0);
}

// ---------------- weight fp32 -> bf16 convert (1M elements) ----------------
__global__ __launch_bounds__(256) void cvt_f32_bf16(const float* __restrict__ in,
                                                    unsigned short* __restrict__ out) {
  const int i = (blockIdx.x * 256 + threadIdx.x) * 4;  // grid covers exactly 1<<20
  f32x4 v = *(const f32x4*)(in + i);
  u32x2 w;
  w[0] = f2bf(v[0]) | ((unsigned)f2bf(v[1]) << 16);
  w[1] = f2bf(v[2]) | ((unsigned)f2bf(v[3]) << 16);
  *(u32x2*)(out + i) = w;
}

// ---------------- GEMM: Y[M,N] = X[M,K] @ W[N,K]^T + b ----------------
// A_FP32: A operand is fp32 (reg-staged + cvt into padded LDS); else bf16 via global_load_lds.
// OUT_MODE: 0 = bf16 row-major [M,1024]; 1 = fp32 row-major (d_out);
//           2 = bf16 transposed per head: Vt_g[b][h][d][s]  (for attention V)
template <int A_FP32, int OUT_MODE>
__global__ __launch_bounds__(256) void gemm128(const void* __restrict__ Ap,
                                               const unsigned short* __restrict__ Bw,
                                               const float* __restrict__ bias,
                                               void* __restrict__ Outp) {
  constexpr int ASTR = A_FP32 ? 40 : 32;  // pad fp32-staged A rows: stride 40 elems -> 2-way banks (free)
  __shared__ unsigned short As[128 * ASTR];
  __shared__ unsigned short Bs[128 * 32];

  const int tid = threadIdx.x;
  const int lane = tid & 63, wid = tid >> 6;
  const int l16 = lane & 15, lg = lane >> 4;
  const int wrow = (wid >> 1) * 64, wcol = (wid & 1) * 64;

  // XCD-aware bijective swizzle (512 blocks % 8 == 0)
  const int bx = blockIdx.x;
  const int swz = (bx & 7) * 64 + (bx >> 3);
  const int m0 = (swz >> 3) * 128, n0 = (swz & 7) * 128;

  f32x4 acc[4][4];
  const f32x4 zero = {0.f, 0.f, 0.f, 0.f};
#pragma unroll
  for (int i = 0; i < 4; ++i)
#pragma unroll
    for (int j = 0; j < 4; ++j) acc[i][j] = zero;

#pragma unroll 1
  for (int kt = 0; kt < D_MODEL / 32; ++kt) {
    const int k0 = kt * 32;
    __syncthreads();
    if constexpr (A_FP32) {
      const float* Af = (const float*)Ap;
      const int ar = tid >> 1, ah = (tid & 1) * 16;
      const float* src = Af + (size_t)(m0 + ar) * D_MODEL + k0 + ah;
      f32x4 v0 = *(const f32x4*)src;
      f32x4 v1 = *(const f32x4*)(src + 4);
      f32x4 v2 = *(const f32x4*)(src + 8);
      f32x4 v3 = *(const f32x4*)(src + 12);
      u32x4 pa, pb;
      pa[0] = f2bf(v0[0]) | ((unsigned)f2bf(v0[1]) << 16);
      pa[1] = f2bf(v0[2]) | ((unsigned)f2bf(v0[3]) << 16);
      pa[2] = f2bf(v1[0]) | ((unsigned)f2bf(v1[1]) << 16);
      pa[3] = f2bf(v1[2]) | ((unsigned)f2bf(v1[3]) << 16);
      pb[0] = f2bf(v2[0]) | ((unsigned)f2bf(v2[1]) << 16);
      pb[1] = f2bf(v2[2]) | ((unsigned)f2bf(v2[3]) << 16);
      pb[2] = f2bf(v3[0]) | ((unsigned)f2bf(v3[1]) << 16);
      pb[3] = f2bf(v3[2]) | ((unsigned)f2bf(v3[3]) << 16);
      *(u32x4*)&As[ar * ASTR + ah] = pa;
      *(u32x4*)&As[ar * ASTR + ah + 8] = pb;
    } else {
      const unsigned short* Ab = (const unsigned short*)Ap;
      const unsigned short* srcb = Ab + (size_t)m0 * D_MODEL + k0;
#pragma unroll
      for (int p = 0; p < 2; ++p) {
        const int e = wid * 512 + p * 2048 + lane * 8;  // element idx in 128x32 tile
        gl_lds16(srcb + (size_t)(e >> 5) * D_MODEL + (e & 31),
                 (char*)As + wid * 1024 + p * 4096);
      }
    }
    {
      const unsigned short* srcb = Bw + (size_t)n0 * D_MODEL + k0;
#pragma unroll
      for (int p = 0; p < 2; ++p) {
        const int e = wid * 512 + p * 2048 + lane * 8;
        gl_lds16(srcb + (size_t)(e >> 5) * D_MODEL + (e & 31),
                 (char*)Bs + wid * 1024 + p * 4096);
      }
    }
    __syncthreads();

    bf16x8 af[4], bfr[4];
#pragma unroll
    for (int i = 0; i < 4; ++i) {
      af[i]  = *(const bf16x8*)&As[(wrow + i * 16 + l16) * ASTR + lg * 8];
      bfr[i] = *(const bf16x8*)&Bs[(wcol + i * 16 + l16) * 32 + lg * 8];
    }
#pragma unroll
    for (int i = 0; i < 4; ++i)
#pragma unroll
      for (int j = 0; j < 4; ++j)
        acc[i][j] = __builtin_amdgcn_mfma_f32_16x16x32_bf16(af[i], bfr[j], acc[i][j], 0, 0, 0);
  }

  // epilogue: + bias, store
#pragma unroll
  for (int j = 0; j < 4; ++j) {
    const int col = n0 + wcol + j * 16 + l16;
    const float bv = bias[col];
    if constexpr (OUT_MODE == 2) {
      const int hh = col >> 6, dd = col & 63;
#pragma unroll
      for (int i = 0; i < 4; ++i) {
        const int row0 = m0 + wrow + i * 16 + lg * 4;
        u32x2 pw;
        pw[0] = f2bf(acc[i][j][0] + bv) | ((unsigned)f2bf(acc[i][j][1] + bv) << 16);
        pw[1] = f2bf(acc[i][j][2] + bv) | ((unsigned)f2bf(acc[i][j][3] + bv) << 16);
        unsigned short* dst = (unsigned short*)Outp +
            ((((size_t)(row0 >> 11) * HEADS + hh) * DK + dd) * SEQ + (row0 & (SEQ - 1)));
        *(u32x2*)dst = pw;
      }
    } else {
#pragma unroll
      for (int i = 0; i < 4; ++i) {
        const int row0 = m0 + wrow + i * 16 + lg * 4;
#pragma unroll
        for (int r = 0; r < 4; ++r) {
          const float y = acc[i][j][r] + bv;
          if constexpr (OUT_MODE == 1)
            ((float*)Outp)[(size_t)(row0 + r) * D_MODEL + col] = y;
          else
            ((unsigned short*)Outp)[(size_t)(row0 + r) * D_MODEL + col] = f2bf(y);
        }
      }
    }
  }
}

// ---------------- flash attention v2: swapped QK^T, in-lane softmax ----------------
// Grid: 1024 blocks = 16 q-blocks x 64 (b,h); 4 waves/block, 32 q-rows/wave.
__global__ __launch_bounds__(256) void attn_v2(const unsigned short* __restrict__ Qb,
                                               const unsigned short* __restrict__ Kb,
                                               const unsigned short* __restrict__ Vtg,
                                               unsigned short* __restrict__ Xo) {
  __shared__ unsigned short Ks[64 * 72];       // K tile [t][dk], stride 72
  __shared__ unsigned short Vt[64 * 72];       // V^T tile [d][t], stride 72
  __shared__ unsigned short Ps[4][32 * 72];    // per-wave P [q][t]

  const int tid = threadIdx.x;
  const int lane = tid & 63, w = tid >> 6;
  const int l16 = lane & 15, lg = lane >> 4;
  const int qb = blockIdx.x & 15, bh = blockIdx.x >> 4;
  const int b = bh >> 4, h = bh & 15;

  const size_t srow0 = (size_t)b * SEQ + qb * 128;
  const unsigned short* Qp = Qb + srow0 * D_MODEL + h * DK;
  const unsigned short* Kp = Kb + (size_t)b * SEQ * D_MODEL + h * DK;
  const unsigned short* Vp = Vtg + (size_t)bh * DK * SEQ;

  const int sr = tid >> 2;            // staging row 0..63
  const int scol = (tid & 3) * 16;    // staging col 0/16/32/48

  // Q fragments (B-operand): q = w*32 + qf*16 + l16, k = kh*32 + lg*8
  bf16x8 qfrag[2][2];
#pragma unroll
  for (int qf = 0; qf < 2; ++qf)
#pragma unroll
    for (int kh = 0; kh < 2; ++kh)
      qfrag[qf][kh] = *(const bf16x8*)(Qp + (size_t)(w * 32 + qf * 16 + l16) * D_MODEL + kh * 32 + lg * 8);

  // prefetch kb = 0 into registers (T14)
  u32x4 kr0, kr1, vr0, vr1;
  {
    const unsigned short* ksrc = Kp + (size_t)sr * D_MODEL + scol;
    kr0 = *(const u32x4*)ksrc; kr1 = *(const u32x4*)(ksrc + 8);
    const unsigned short* vsrc = Vp + (size_t)sr * SEQ + scol;
    vr0 = *(const u32x4*)vsrc; vr1 = *(const u32x4*)(vsrc + 8);
  }

  float mrun[2], lrun[2];
  f32x4 acco[2][4];
  const f32x4 zero = {0.f, 0.f, 0.f, 0.f};
#pragma unroll
  for (int qf = 0; qf < 2; ++qf) {
    mrun[qf] = -1e30f; lrun[qf] = 0.f;
#pragma unroll
    for (int df = 0; df < 4; ++df) acco[qf][df] = zero;
  }

  const float SC = 0.125f * 1.4426950408889634f;  // 1/sqrt(dk) * log2(e)
  unsigned short* Psw = Ps[w];
  const int srcbase = (lane & 48) | ((lane & 48) >> 2);  // 16*lg + 4*lg

#pragma unroll 1
  for (int kb = 0; kb < SEQ / 64; ++kb) {
    __syncthreads();  // prior iteration's LDS reads done
    *(u32x4*)&Ks[sr * 72 + scol] = kr0;
    *(u32x4*)&Ks[sr * 72 + scol + 8] = kr1;
    *(u32x4*)&Vt[sr * 72 + scol] = vr0;
    *(u32x4*)&Vt[sr * 72 + scol + 8] = vr1;
    __syncthreads();
    if (kb + 1 < SEQ / 64) {  // issue next tile's loads; latency hides under compute
      const unsigned short* ksrc = Kp + (size_t)((kb + 1) * 64 + sr) * D_MODEL + scol;
      kr0 = *(const u32x4*)ksrc; kr1 = *(const u32x4*)(ksrc + 8);
      const unsigned short* vsrc = Vp + (size_t)sr * SEQ + (kb + 1) * 64 + scol;
      vr0 = *(const u32x4*)vsrc; vr1 = *(const u32x4*)(vsrc + 8);
    }

    // QK^T swapped: sc[qf][tf] = S^T tile (rows t, cols q)
    f32x4 sc[2][4];
#pragma unroll
    for (int qf = 0; qf < 2; ++qf)
#pragma unroll
      for (int tf = 0; tf < 4; ++tf) sc[qf][tf] = zero;
#pragma unroll
    for (int tf = 0; tf < 4; ++tf) {
      bf16x8 k0 = *(const bf16x8*)&Ks[(tf * 16 + l16) * 72 + lg * 8];
      bf16x8 k1 = *(const bf16x8*)&Ks[(tf * 16 + l16) * 72 + 32 + lg * 8];
#pragma unroll
      for (int qf = 0; qf < 2; ++qf) {
        sc[qf][tf] = __builtin_amdgcn_mfma_f32_16x16x32_bf16(k0, qfrag[qf][0], sc[qf][tf], 0, 0, 0);
        sc[qf][tf] = __builtin_amdgcn_mfma_f32_16x16x32_bf16(k1, qfrag[qf][1], sc[qf][tf], 0, 0, 0);
      }
    }

    // online softmax: lane owns column q = qf*16 + l16 (16 t-values in-lane)
#pragma unroll
    for (int qf = 0; qf < 2; ++qf) {
      float mx = fmaxf(fmaxf(sc[qf][0][0], sc[qf][0][1]), fmaxf(sc[qf][0][2], sc[qf][0][3]));
#pragma unroll
      for (int tf = 1; tf < 4; ++tf) {
        mx = fmaxf(mx, fmaxf(fmaxf(sc[qf][tf][0], sc[qf][tf][1]),
                             fmaxf(sc[qf][tf][2], sc[qf][tf][3])));
      }
      mx = fmaxf(mx, __shfl_xor(mx, 16));
      mx = fmaxf(mx, __shfl_xor(mx, 32));
      const float mxs = mx * SC;
      if (__ballot(mxs > mrun[qf] + 8.f)) {  // T13 defer-max: rescale only on real growth
        const float mnew = fmaxf(mrun[qf], mxs);
        const float rs = __builtin_amdgcn_exp2f(mrun[qf] - mnew);
        mrun[qf] = mnew;
        lrun[qf] *= rs;
#pragma unroll
        for (int r = 0; r < 4; ++r) {
          const float rr = __shfl(rs, srcbase + r);  // resc for acc row q = qf*16+lg*4+r
#pragma unroll
          for (int df = 0; df < 4; ++df) acco[qf][df][r] *= rr;
        }
      }
      const float m = mrun[qf];
      float sum = 0.f;
#pragma unroll
      for (int tf = 0; tf < 4; ++tf) {
#pragma unroll
        for (int r = 0; r < 4; ++r) {
          const float p = __builtin_amdgcn_exp2f(fmaf(sc[qf][tf][r], SC, -m));
          sc[qf][tf][r] = p;
          sum += p;
        }
      }
      sum += __shfl_xor(sum, 16);
      sum += __shfl_xor(sum, 32);
      lrun[qf] += sum;
      // pack P row q: 4 consecutive t per (tf): one ds_write_b64
#pragma unroll
      for (int tf = 0; tf < 4; ++tf) {
        u32x2 pw;
        pw[0] = f2bf(sc[qf][tf][0]) | ((unsigned)f2bf(sc[qf][tf][1]) << 16);
        pw[1] = f2bf(sc[qf][tf][2]) | ((unsigned)f2bf(sc[qf][tf][3]) << 16);
        *(u32x2*)&Psw[(qf * 16 + l16) * 72 + tf * 16 + lg * 4] = pw;
      }
    }

    // PV: O[q][d] += P[q][t] @ Vt[d][t]
    bf16x8 pf[2][2];
#pragma unroll
    for (int qf = 0; qf < 2; ++qf)
#pragma unroll
      for (int k2 = 0; k2 < 2; ++k2)
        pf[qf][k2] = *(const bf16x8*)&Psw[(qf * 16 + l16) * 72 + k2 * 32 + lg * 8];
#pragma unroll
    for (int df = 0; df < 4; ++df) {
      bf16x8 v0 = *(const bf16x8*)&Vt[(df * 16 + l16) * 72 + lg * 8];
      bf16x8 v1 = *(const bf16x8*)&Vt[(df * 16 + l16) * 72 + 32 + lg * 8];
#pragma unroll
      for (int qf = 0; qf < 2; ++qf) {
        acco[qf][df] = __builtin_amdgcn_mfma_f32_16x16x32_bf16(pf[qf][0], v0, acco[qf][df], 0, 0, 0);
        acco[qf][df] = __builtin_amdgcn_mfma_f32_16x16x32_bf16(pf[qf][1], v1, acco[qf][df], 0, 0, 0);
      }
    }
  }

  // finalize: /= l, store bf16 to X (layout [B*S, H*DK])
  unsigned short* dst = Xo + (srow0 + w * 32) * D_MODEL + h * DK;
#pragma unroll
  for (int qf = 0; qf < 2; ++qf) {
    const float inv = 1.f / lrun[qf];
#pragma unroll
    for (int r = 0; r < 4; ++r) {
      const float rr = __shfl(inv, srcbase + r);
      const int row = qf * 16 + lg * 4 + r;
#pragma unroll
      for (int df = 0; df < 4; ++df)
        dst[(size_t)row * D_MODEL + df * 16 + l16] = f2bf(acco[qf][df][r] * rr);
    }
  }
}

extern "C" void kernel_launch(void* const* d_in, const int* in_sizes, int n_in,
                              void* d_out, int out_size, void* d_ws, size_t ws_size,
                              hipStream_t stream) {
  const float* query = (const float*)d_in[0];
  const float* key_  = (const float*)d_in[1];
  const float* value = (const float*)d_in[2];
  const float* Wq = (const float*)d_in[3];
  const float* bq = (const float*)d_in[4];
  const float* Wk = (const float*)d_in[5];
  const float* bk = (const float*)d_in[6];
  const float* Wv = (const float*)d_in[7];
  const float* bv = (const float*)d_in[8];
  const float* Wo = (const float*)d_in[9];
  const float* bo = (const float*)d_in[10];

  // workspace layout (bf16 elements): 4x 1M weights, 4x 8M activations = 72 MB
  unsigned short* ws  = (unsigned short*)d_ws;
  unsigned short* WqB = ws;
  unsigned short* WkB = WqB + (1u << 20);
  unsigned short* WvB = WkB + (1u << 20);
  unsigned short* WoB = WvB + (1u << 20);
  unsigned short* Qb  = WoB + (1u << 20);
  unsigned short* Kb  = Qb + (size_t)MROWS * D_MODEL;
  unsigned short* Vtg = Kb + (size_t)MROWS * D_MODEL;  // [b][h][d][s]
  unsigned short* Xb  = Vtg + (size_t)MROWS * D_MODEL;
  if (ws_size < (size_t)(4u * (1u << 20) + 4u * (size_t)MROWS * D_MODEL) * 2u) return;

  cvt_f32_bf16<<<1024, 256, 0, stream>>>(Wq, WqB);
  cvt_f32_bf16<<<1024, 256, 0, stream>>>(Wk, WkB);
  cvt_f32_bf16<<<1024, 256, 0, stream>>>(Wv, WvB);
  cvt_f32_bf16<<<1024, 256, 0, stream>>>(Wo, WoB);

  gemm128<1, 0><<<512, 256, 0, stream>>>(query, WqB, bq, Qb);
  gemm128<1, 0><<<512, 256, 0, stream>>>(key_,  WkB, bk, Kb);
  gemm128<1, 2><<<512, 256, 0, stream>>>(value, WvB, bv, Vtg);  // writes V^T per head

  attn_v2<<<1024, 256, 0, stream>>>(Qb, Kb, Vtg, Xb);

  gemm128<0, 1><<<512, 256, 0, stream>>>(Xb, WoB, bo, (float*)d_out);
}